// Round 12
// baseline (321.966 us; speedup 1.0000x reference)
//
#include <hip/hip_runtime.h>

// HMM forward: alpha_t = (alpha_{t-1} @ A) * B[:, obs[t]]; out[t][s] = alpha_t[s].
// S=2048, T=8192, 512 symbols, fp32.
//
// alpha decays ~512x/step -> exact-zero underflow at t~17; after the first
// all-zero row every later row is zero (verified R1-R15, absmax 1e-38).
// Honest recurrence + all-zero detection + zero tail (separate kernel).
//
// R16-R19 post-mortem: 4 consecutive no-data harness failures (Trio/container
// alternating) on the fully-decoupled barrier-free design -- including R19
// which carried a provably-live system-scope+sleep fallback. Infra-flake is
// the best fit (R6 showed 587s pushes), but 4 strikes = stop resubmitting.
// The ONE novel runtime dynamic of R16-R19 was 1024 fully-decoupled waves
// spread across different steps. R20 removes it:
// HYBRID: keep R16's per-wave full-row poll + 2-column end-to-end ownership
// (NO LDS round-trip, NO serialized wave0 combine -- the intra-block overhead
// this redesign targets), but reinstate one per-step __syncthreads() after
// publish, restoring the R8-R15 proven lockstep cadence. Barrier-safe break:
// the all-zero verdict comes from the full row, so it is block-uniform --
// all 16 waves break together, none strands at the barrier.
// Poll fallback kept from R19: 8192 device-scope spins, then system-scope +
// s_sleep(1) (the R1-R14 proven-live mechanism). Publishes system-scope
// (R15 A/B: system == device in time).
//
// Per-step critical path now: publish -> cross-XCD visibility -> poll ->
// 64 FMA + butterfly -> publish. Intra-block adds only one bare barrier.
//
// Encoding: enc = bits(a)+2^30 in [0x40000000,0x7F800000] (alpha in [0,1]);
// poison 0xAA.. (negative as int), zeros, and never-written slots all read
// not-ready via raw signed compare e < READY.
//
// k2 hmm_tail (256 blocks): decode rows < zstart in place, zero rows >=
// zstart. Kernel boundary = HW global barrier with full visibility.
// flag[0] = zstart (lastRow+1), same value from every block (benign).

#define S     2048
#define T     8192
#define NSYM  512
#define NCBLK 64                         // recurrence blocks
#define NTHR  1024
#define FBLK  256                        // tail-kernel blocks
#define READY 0x40000000
#define SPIN_FAST 8192                   // device-scope spin budget (~1ms)

typedef int   v2i __attribute__((ext_vector_type(2)));
typedef int   v4i __attribute__((ext_vector_type(4)));

__device__ __forceinline__ void store_sys_i2(int* p, v2i v) {
    asm volatile("global_store_dwordx2 %0, %1, off sc0 sc1"   // system scope
                 :: "v"(p), "v"(v) : "memory");
}

// 8 dwordx4 loads of the lane's contiguous 128B row slice -- device scope.
#define POLL32_DEV(E0,E1,E2,E3,E4,E5,E6,E7,bp)                              \
    asm volatile("global_load_dwordx4 %0, %8, off sc1\n\t"                  \
                 "global_load_dwordx4 %1, %8, off offset:16 sc1\n\t"        \
                 "global_load_dwordx4 %2, %8, off offset:32 sc1\n\t"        \
                 "global_load_dwordx4 %3, %8, off offset:48 sc1\n\t"        \
                 "global_load_dwordx4 %4, %8, off offset:64 sc1\n\t"        \
                 "global_load_dwordx4 %5, %8, off offset:80 sc1\n\t"        \
                 "global_load_dwordx4 %6, %8, off offset:96 sc1\n\t"        \
                 "global_load_dwordx4 %7, %8, off offset:112 sc1"           \
                 : "=&v"(E0), "=&v"(E1), "=&v"(E2), "=&v"(E3),              \
                   "=&v"(E4), "=&v"(E5), "=&v"(E6), "=&v"(E7)               \
                 : "v"(bp) : "memory")

// Same, system scope (proven-live R1-R14 mechanism) for the fallback path.
#define POLL32_SYS(E0,E1,E2,E3,E4,E5,E6,E7,bp)                              \
    asm volatile("global_load_dwordx4 %0, %8, off sc0 sc1\n\t"              \
                 "global_load_dwordx4 %1, %8, off offset:16 sc0 sc1\n\t"    \
                 "global_load_dwordx4 %2, %8, off offset:32 sc0 sc1\n\t"    \
                 "global_load_dwordx4 %3, %8, off offset:48 sc0 sc1\n\t"    \
                 "global_load_dwordx4 %4, %8, off offset:64 sc0 sc1\n\t"    \
                 "global_load_dwordx4 %5, %8, off offset:80 sc0 sc1\n\t"    \
                 "global_load_dwordx4 %6, %8, off offset:96 sc0 sc1\n\t"    \
                 "global_load_dwordx4 %7, %8, off offset:112 sc0 sc1"       \
                 : "=&v"(E0), "=&v"(E1), "=&v"(E2), "=&v"(E3),              \
                   "=&v"(E4), "=&v"(E5), "=&v"(E6), "=&v"(E7)               \
                 : "v"(bp) : "memory")

__global__ void __launch_bounds__(NTHR) hmm_fwd(
    const int*   __restrict__ obs,
    const float* __restrict__ A,
    const float* __restrict__ B,
    const float* __restrict__ pi,
    float*       __restrict__ out,
    unsigned*    __restrict__ flag)
{
    const int tx   = threadIdx.x;
    const int b    = blockIdx.x;
    const int lane = tx & 63;
    const int w    = tx >> 6;            // wave id 0..15
    const int c0   = b * 32 + 2 * w;     // this wave's two output columns

    // ---- step 0 FIRST: each wave's lane0 publishes its 2 cols of alpha0 ----
    if (lane == 0) {
        const int o0 = obs[0];
        const float f0 = pi[c0]     * B[(size_t)c0       * NSYM + o0];
        const float f1 = pi[c0 + 1] * B[(size_t)(c0 + 1) * NSYM + o0];
        v2i e;
        e.x = __float_as_int(f0) + READY;
        e.y = __float_as_int(f1) + READY;
        store_sys_i2((int*)out + c0, e);
    }

    // ---- A-hoist: lane l holds A[32l+ki][c0..c0+1] as 32 float2 (64 VGPR) ----
    const float2* A2 = (const float2*)A;
    float2 a2[32];
    #pragma unroll
    for (int ki = 0; ki < 32; ++ki)
        a2[ki] = A2[(size_t)(lane * 32 + ki) * (S / 2) + (c0 >> 1)];

    int lastRow = T - 1;

    for (int t = 1; t < T; ++t) {
        // ---- emission prefetch (lane0 only; used only by lane0's publish) ----
        float em0 = 0.f, em1 = 0.f;
        if (lane == 0) {
            const int o = obs[t];
            em0 = B[(size_t)c0       * NSYM + o];
            em1 = B[(size_t)(c0 + 1) * NSYM + o];
        }

        // ---- poll this lane's contiguous 32 encoded scalars of row t-1 ----
        // fast path: device scope; after SPIN_FAST iters: system scope + sleep.
        const int* vb = (const int*)(out + (size_t)(t - 1) * S) + lane * 32;
        v4i E0, E1, E2, E3, E4, E5, E6, E7;
        for (int spins = 0; ; ++spins) {
            if (spins < SPIN_FAST) {
                POLL32_DEV(E0, E1, E2, E3, E4, E5, E6, E7, vb);
            } else {
                POLL32_SYS(E0, E1, E2, E3, E4, E5, E6, E7, vb);
            }
            asm volatile("s_waitcnt vmcnt(0)" ::: "memory");
            const int ok =
                (E0.x >= READY) & (E0.y >= READY) & (E0.z >= READY) & (E0.w >= READY) &
                (E1.x >= READY) & (E1.y >= READY) & (E1.z >= READY) & (E1.w >= READY) &
                (E2.x >= READY) & (E2.y >= READY) & (E2.z >= READY) & (E2.w >= READY) &
                (E3.x >= READY) & (E3.y >= READY) & (E3.z >= READY) & (E3.w >= READY) &
                (E4.x >= READY) & (E4.y >= READY) & (E4.z >= READY) & (E4.w >= READY) &
                (E5.x >= READY) & (E5.y >= READY) & (E5.z >= READY) & (E5.w >= READY) &
                (E6.x >= READY) & (E6.y >= READY) & (E6.z >= READY) & (E6.w >= READY) &
                (E7.x >= READY) & (E7.y >= READY) & (E7.z >= READY) & (E7.w >= READY);
            if (__all(ok)) break;
            if (spins >= SPIN_FAST) __builtin_amdgcn_s_sleep(1);
        }

        // ---- decode + FMA vs register-resident A (both columns) ----
        int nz = 0;
        float acc0 = 0.f, acc1 = 0.f;
        #define STEP1(E, C, KI)                                                \
            { const int d = (E).C - READY; nz |= d;                            \
              const float af = __int_as_float(d);                              \
              acc0 = fmaf(af, a2[KI].x, acc0);                                 \
              acc1 = fmaf(af, a2[KI].y, acc1); }
        STEP1(E0,x, 0) STEP1(E0,y, 1) STEP1(E0,z, 2) STEP1(E0,w, 3)
        STEP1(E1,x, 4) STEP1(E1,y, 5) STEP1(E1,z, 6) STEP1(E1,w, 7)
        STEP1(E2,x, 8) STEP1(E2,y, 9) STEP1(E2,z,10) STEP1(E2,w,11)
        STEP1(E3,x,12) STEP1(E3,y,13) STEP1(E3,z,14) STEP1(E3,w,15)
        STEP1(E4,x,16) STEP1(E4,y,17) STEP1(E4,z,18) STEP1(E4,w,19)
        STEP1(E5,x,20) STEP1(E5,y,21) STEP1(E5,z,22) STEP1(E5,w,23)
        STEP1(E6,x,24) STEP1(E6,y,25) STEP1(E6,z,26) STEP1(E6,w,27)
        STEP1(E7,x,28) STEP1(E7,y,29) STEP1(E7,z,30) STEP1(E7,w,31)
        #undef STEP1

        // wave-wide verdict on the FULL row t-1 -- identical in every wave of
        // every block (rows are write-once). Break BEFORE publishing row t;
        // uniform across the block, so the skipped barrier strands nobody.
        const unsigned long long nzm = __ballot(nz != 0);
        if (nzm == 0ull) { lastRow = t - 1; break; }

        // ---- full-wave butterfly reduce, both columns ----
        #pragma unroll
        for (int m = 1; m <= 32; m <<= 1) {
            acc0 += __shfl_xor(acc0, m);
            acc1 += __shfl_xor(acc1, m);
        }

        // ---- lane0 publishes this wave's 2 encoded outputs of row t ----
        if (lane == 0) {
            v2i e;
            e.x = __float_as_int(acc0 * em0) + READY;
            e.y = __float_as_int(acc1 * em1) + READY;
            store_sys_i2((int*)(out + (size_t)t * S) + c0, e);
        }

        // ---- lockstep pacing (R8-R15 proven cadence); bare barrier only ----
        __syncthreads();
    }

    // ---- publish zstart; kernel boundary handles ordering/visibility ----
    if (tx == 0)
        __hip_atomic_store(&flag[0], (unsigned)(lastRow + 1), __ATOMIC_RELAXED,
                           __HIP_MEMORY_SCOPE_AGENT);
}

// k2: decode rows [0, zstart), zero rows [zstart, T). Stream-ordered after k1;
// the kernel boundary guarantees k1's stores are visible to plain loads here.
__global__ void __launch_bounds__(NTHR) hmm_tail(
    float*          __restrict__ out,
    const unsigned* __restrict__ flag)
{
    const unsigned zstart = flag[0];                 // lastRow+1
    const size_t total4 = (size_t)T * (S / 4);       // float4 count
    v4i* o4 = (v4i*)out;
    const v4i zero = {0, 0, 0, 0};
    for (size_t i = (size_t)blockIdx.x * NTHR + threadIdx.x; i < total4;
         i += (size_t)FBLK * NTHR) {
        const unsigned r = (unsigned)(i >> 9);       // S/4 = 512 float4 per row
        if (r >= zstart) {
            o4[i] = zero;                            // plain coalesced store
        } else {
            v4i e = o4[i];                           // plain load (post-barrier)
            e.x -= READY; e.y -= READY; e.z -= READY; e.w -= READY;
            o4[i] = e;
        }
    }
}

extern "C" void kernel_launch(void* const* d_in, const int* in_sizes, int n_in,
                              void* d_out, int out_size, void* d_ws, size_t ws_size,
                              hipStream_t stream) {
    const int*   obs = (const int*)d_in[0];
    const float* A   = (const float*)d_in[1];
    const float* B   = (const float*)d_in[2];
    const float* pi  = (const float*)d_in[3];
    float* out = (float*)d_out;
    unsigned* flag = (unsigned*)d_ws;

    // d_ws is poisoned before every launch; zstart word must start defined.
    (void)hipMemsetAsync(d_ws, 0, 4 * sizeof(unsigned), stream);

    hmm_fwd<<<dim3(NCBLK), dim3(NTHR), 0, stream>>>(obs, A, B, pi, out, flag);
    hmm_tail<<<dim3(FBLK), dim3(NTHR), 0, stream>>>(out, flag);
}

// Round 13
// 204.622 us; speedup vs baseline: 1.5735x; 1.5735x over previous
//
#include <hip/hip_runtime.h>

// HMM forward: alpha_t = (alpha_{t-1} @ A) * B[:, obs[t]]; out[t][s] = alpha_t[s].
// S=2048, T=8192, 512 symbols, fp32.
//
// alpha decays ~512x/step -> exact-zero underflow at t~17; honest recurrence
// + all-zero detection + zero tail (separate kernel). absmax 1e-38 R1-R20.
//
// R20 post-mortem (ran, 245us -- 5x regression, counters decisive):
// (a) every wave polled the full 8KB row -> 1024 waves x 8KB = 8MB/round of
//     coherent fabric traffic (R15: 512KB) -- poll storm poisons the fabric
//     the publishes must cross (R10's lesson, re-measured);
// (b) 16x scattered 8B system-scope stores/block -> WRITE_SIZE 130KB->3.6MB
//     (26x line-RMW amplification).
// Constraints learned: keep aggregate poll ~512KB/round; publishes few x 16B.
// R21: poller-wave + LDS broadcast. Per block (9 waves, 576 thr):
//   wave 8 = POLLER: polls full row (64 pollers total = 512KB/round OK),
//     8x dwordx4/lane contiguous; computes all-zero verdict; writes row to
//     LDS buf[t&1] (linear); fence; writes LDS seq-flag = (t<<1)|nz.
//   waves 0..7 = COMPUTE: spin on LDS flag (ZERO fabric traffic), read row
//     from LDS with stride-64 k-mapping (lane l reads k=l+64ki -> bank =
//     l%32, 2-way = free), FMA vs 32x float4 register A (4 cols/wave),
//     6-level butterfly, lane0 publishes 16B contiguous (8 stores/block =
//     R15's exact proven store pattern).
// No per-step barrier/LDS-combine/wave0 second stage. Double-buffered LDS
// row + per-wave done-stamps handle WAR. One __syncthreads total (init).
// Poller keeps R19 liveness fallback (8192 dev-scope spins -> sys+sleep).
// All-zero break: poller's verdict is broadcast in the flag -> all waves of
// all blocks break at the same t (write-once rows => identical verdicts).
//
// Encoding: enc = bits(a)+2^30 in [0x40000000,0x7F800000] (alpha in [0,1]);
// poison 0xAA.. (negative), zeros, stale decoded [0,1] floats all read
// not-ready via signed compare e < READY.
//
// k2 hmm_tail (256 blocks): decode rows < zstart, zero rows >= zstart.
// flag[0] (d_ws) = zstart, written by compute wave0 lane0 of every block.

#define S     2048
#define T     8192
#define NSYM  512
#define NCBLK 64                         // recurrence blocks
#define CTHR  576                        // 9 waves: 8 compute + 1 poller
#define FBLK  256                        // tail-kernel blocks
#define NTHR  1024                       // tail-kernel threads
#define READY 0x40000000
#define SPIN_FAST 8192                   // device-scope spin budget (~1ms)

typedef int   v4i __attribute__((ext_vector_type(4)));

__device__ __forceinline__ void store_sys_i4(int* p, v4i v) {
    asm volatile("global_store_dwordx4 %0, %1, off sc0 sc1"   // system scope
                 :: "v"(p), "v"(v) : "memory");
}

// 8 dwordx4 loads of the lane's contiguous 128B row slice -- device scope.
#define POLL32_DEV(E0,E1,E2,E3,E4,E5,E6,E7,bp)                              \
    asm volatile("global_load_dwordx4 %0, %8, off sc1\n\t"                  \
                 "global_load_dwordx4 %1, %8, off offset:16 sc1\n\t"        \
                 "global_load_dwordx4 %2, %8, off offset:32 sc1\n\t"        \
                 "global_load_dwordx4 %3, %8, off offset:48 sc1\n\t"        \
                 "global_load_dwordx4 %4, %8, off offset:64 sc1\n\t"        \
                 "global_load_dwordx4 %5, %8, off offset:80 sc1\n\t"        \
                 "global_load_dwordx4 %6, %8, off offset:96 sc1\n\t"        \
                 "global_load_dwordx4 %7, %8, off offset:112 sc1"           \
                 : "=&v"(E0), "=&v"(E1), "=&v"(E2), "=&v"(E3),              \
                   "=&v"(E4), "=&v"(E5), "=&v"(E6), "=&v"(E7)               \
                 : "v"(bp) : "memory")

// Same, system scope (R1-R14 proven-live mechanism) for the fallback path.
#define POLL32_SYS(E0,E1,E2,E3,E4,E5,E6,E7,bp)                              \
    asm volatile("global_load_dwordx4 %0, %8, off sc0 sc1\n\t"              \
                 "global_load_dwordx4 %1, %8, off offset:16 sc0 sc1\n\t"    \
                 "global_load_dwordx4 %2, %8, off offset:32 sc0 sc1\n\t"    \
                 "global_load_dwordx4 %3, %8, off offset:48 sc0 sc1\n\t"    \
                 "global_load_dwordx4 %4, %8, off offset:64 sc0 sc1\n\t"    \
                 "global_load_dwordx4 %5, %8, off offset:80 sc0 sc1\n\t"    \
                 "global_load_dwordx4 %6, %8, off offset:96 sc0 sc1\n\t"    \
                 "global_load_dwordx4 %7, %8, off offset:112 sc0 sc1"       \
                 : "=&v"(E0), "=&v"(E1), "=&v"(E2), "=&v"(E3),              \
                   "=&v"(E4), "=&v"(E5), "=&v"(E6), "=&v"(E7)               \
                 : "v"(bp) : "memory")

__global__ void __launch_bounds__(CTHR) hmm_fwd(
    const int*   __restrict__ obs,
    const float* __restrict__ A,
    const float* __restrict__ B,
    const float* __restrict__ pi,
    float*       __restrict__ out,
    unsigned*    __restrict__ flag)
{
    __shared__ int           lbuf[2][S];     // double-buffered encoded row, 16KB
    __shared__ volatile int  lflag[2];       // seq-flag: (t<<1)|nz
    __shared__ volatile int  ldone[2][8];    // per-compute-wave done-stamp

    const int tx   = threadIdx.x;
    const int b    = blockIdx.x;
    const int lane = tx & 63;
    const int w    = tx >> 6;            // 0..7 compute, 8 poller

    if (tx == 0) {
        lflag[0] = 0; lflag[1] = 0;
        #pragma unroll
        for (int i = 0; i < 8; ++i) { ldone[0][i] = 0; ldone[1][i] = 0; }
    }
    __syncthreads();                     // the ONLY barrier (init)

    if (w == 8) {
        // ======================= POLLER WAVE =======================
        for (int t = 1; t < T; ++t) {
            const int p = t & 1;
            // WAR: readers of buf[p] were step t-2; wait their done-stamps.
            if (t >= 3) {
                for (;;) {
                    int all = 1;
                    #pragma unroll
                    for (int i = 0; i < 8; ++i) all &= (ldone[p][i] == t - 2);
                    if (all) break;
                    __builtin_amdgcn_s_sleep(1);
                }
            }
            // poll global row t-1 (lane l: bytes [128l,128l+128))
            const int* vb = (const int*)(out + (size_t)(t - 1) * S) + lane * 32;
            v4i E0, E1, E2, E3, E4, E5, E6, E7;
            for (int spins = 0; ; ++spins) {
                if (spins < SPIN_FAST) {
                    POLL32_DEV(E0, E1, E2, E3, E4, E5, E6, E7, vb);
                } else {
                    POLL32_SYS(E0, E1, E2, E3, E4, E5, E6, E7, vb);
                }
                asm volatile("s_waitcnt vmcnt(0)" ::: "memory");
                const int ok =
                    (E0.x >= READY) & (E0.y >= READY) & (E0.z >= READY) & (E0.w >= READY) &
                    (E1.x >= READY) & (E1.y >= READY) & (E1.z >= READY) & (E1.w >= READY) &
                    (E2.x >= READY) & (E2.y >= READY) & (E2.z >= READY) & (E2.w >= READY) &
                    (E3.x >= READY) & (E3.y >= READY) & (E3.z >= READY) & (E3.w >= READY) &
                    (E4.x >= READY) & (E4.y >= READY) & (E4.z >= READY) & (E4.w >= READY) &
                    (E5.x >= READY) & (E5.y >= READY) & (E5.z >= READY) & (E5.w >= READY) &
                    (E6.x >= READY) & (E6.y >= READY) & (E6.z >= READY) & (E6.w >= READY) &
                    (E7.x >= READY) & (E7.y >= READY) & (E7.z >= READY) & (E7.w >= READY);
                if (__all(ok)) break;
                if (spins >= SPIN_FAST) __builtin_amdgcn_s_sleep(1);
            }
            // all-zero verdict for row t-1
            int nz = 0;
            nz |= (E0.x-READY)|(E0.y-READY)|(E0.z-READY)|(E0.w-READY);
            nz |= (E1.x-READY)|(E1.y-READY)|(E1.z-READY)|(E1.w-READY);
            nz |= (E2.x-READY)|(E2.y-READY)|(E2.z-READY)|(E2.w-READY);
            nz |= (E3.x-READY)|(E3.y-READY)|(E3.z-READY)|(E3.w-READY);
            nz |= (E4.x-READY)|(E4.y-READY)|(E4.z-READY)|(E4.w-READY);
            nz |= (E5.x-READY)|(E5.y-READY)|(E5.z-READY)|(E5.w-READY);
            nz |= (E6.x-READY)|(E6.y-READY)|(E6.z-READY)|(E6.w-READY);
            nz |= (E7.x-READY)|(E7.y-READY)|(E7.z-READY)|(E7.w-READY);
            const int nzany = (__ballot(nz != 0) != 0ull) ? 1 : 0;
            // broadcast encoded row to LDS (linear; write conflicts ~16-way,
            // ~150ns -- reads are the critical side and they're conflict-free)
            int* dst = &lbuf[p][lane * 32];
            *(v4i*)(dst +  0) = E0;  *(v4i*)(dst +  4) = E1;
            *(v4i*)(dst +  8) = E2;  *(v4i*)(dst + 12) = E3;
            *(v4i*)(dst + 16) = E4;  *(v4i*)(dst + 20) = E5;
            *(v4i*)(dst + 24) = E6;  *(v4i*)(dst + 28) = E7;
            __threadfence_block();                       // drain ds_writes
            if (lane == 0) lflag[p] = (t << 1) | nzany;  // seq-flag
            if (!nzany) break;                           // row t-1 all-zero
        }
    } else {
        // ======================= COMPUTE WAVES =======================
        const int c0 = b * 32 + w * 4;   // this wave's four output columns

        // step 0 publish FIRST (starts the cross-block chain before A-hoist)
        if (lane == 0) {
            const int o0 = obs[0];
            v4i e;
            e.x = __float_as_int(pi[c0+0] * B[(size_t)(c0+0)*NSYM + o0]) + READY;
            e.y = __float_as_int(pi[c0+1] * B[(size_t)(c0+1)*NSYM + o0]) + READY;
            e.z = __float_as_int(pi[c0+2] * B[(size_t)(c0+2)*NSYM + o0]) + READY;
            e.w = __float_as_int(pi[c0+3] * B[(size_t)(c0+3)*NSYM + o0]) + READY;
            store_sys_i4((int*)out + c0, e);
        }

        // A-hoist: a4[ki] = A[lane + 64*ki][c0..c0+3]  (stride-64 k-mapping,
        // matches the conflict-free LDS read pattern; 128 VGPR)
        float4 a4[32];
        #pragma unroll
        for (int ki = 0; ki < 32; ++ki)
            a4[ki] = *(const float4*)&A[(size_t)(lane + 64 * ki) * S + c0];

        int lastRow = T - 1;

        for (int t = 1; t < T; ++t) {
            const int p = t & 1;
            // emission prefetch (lane0; off critical path, hidden by spin)
            float em0 = 0.f, em1 = 0.f, em2 = 0.f, em3 = 0.f;
            if (lane == 0) {
                const int o = obs[t];
                em0 = B[(size_t)(c0+0) * NSYM + o];
                em1 = B[(size_t)(c0+1) * NSYM + o];
                em2 = B[(size_t)(c0+2) * NSYM + o];
                em3 = B[(size_t)(c0+3) * NSYM + o];
            }
            // spin on LDS seq-flag (CU-local, zero fabric traffic)
            int f;
            for (;;) {
                f = lflag[p];
                if ((f >> 1) == t) break;
                __builtin_amdgcn_s_sleep(1);
            }
            if (!(f & 1)) { lastRow = t - 1; break; }    // uniform break
            __threadfence_block();
            asm volatile("" ::: "memory");               // no hoisted LDS reads

            // conflict-free LDS row reads (bank = lane%32, 2-way = free)
            float acc0 = 0.f, acc1 = 0.f, acc2 = 0.f, acc3 = 0.f;
            #pragma unroll
            for (int ki = 0; ki < 32; ++ki) {
                const int e = lbuf[p][lane + 64 * ki];
                const float af = __int_as_float(e - READY);
                acc0 = fmaf(af, a4[ki].x, acc0);
                acc1 = fmaf(af, a4[ki].y, acc1);
                acc2 = fmaf(af, a4[ki].z, acc2);
                acc3 = fmaf(af, a4[ki].w, acc3);
            }
            // full-wave butterfly
            #pragma unroll
            for (int m = 1; m <= 32; m <<= 1) {
                acc0 += __shfl_xor(acc0, m);
                acc1 += __shfl_xor(acc1, m);
                acc2 += __shfl_xor(acc2, m);
                acc3 += __shfl_xor(acc3, m);
            }
            // publish 16B contiguous (8 stores/block = R15-proven pattern)
            if (lane == 0) {
                v4i e;
                e.x = __float_as_int(acc0 * em0) + READY;
                e.y = __float_as_int(acc1 * em1) + READY;
                e.z = __float_as_int(acc2 * em2) + READY;
                e.w = __float_as_int(acc3 * em3) + READY;
                store_sys_i4((int*)(out + (size_t)t * S) + c0, e);
                ldone[p][w] = t;                         // done-stamp (WAR)
            }
        }

        // publish zstart; kernel boundary handles ordering/visibility
        if (tx == 0)
            __hip_atomic_store(&flag[0], (unsigned)(lastRow + 1),
                               __ATOMIC_RELAXED, __HIP_MEMORY_SCOPE_AGENT);
    }
}

// k2: decode rows [0, zstart), zero rows [zstart, T). Stream-ordered after k1.
__global__ void __launch_bounds__(NTHR) hmm_tail(
    float*          __restrict__ out,
    const unsigned* __restrict__ flag)
{
    const unsigned zstart = flag[0];                 // lastRow+1
    const size_t total4 = (size_t)T * (S / 4);       // float4 count
    v4i* o4 = (v4i*)out;
    const v4i zero = {0, 0, 0, 0};
    for (size_t i = (size_t)blockIdx.x * NTHR + threadIdx.x; i < total4;
         i += (size_t)FBLK * NTHR) {
        const unsigned r = (unsigned)(i >> 9);       // S/4 = 512 float4 per row
        if (r >= zstart) {
            o4[i] = zero;
        } else {
            v4i e = o4[i];
            e.x -= READY; e.y -= READY; e.z -= READY; e.w -= READY;
            o4[i] = e;
        }
    }
}

extern "C" void kernel_launch(void* const* d_in, const int* in_sizes, int n_in,
                              void* d_out, int out_size, void* d_ws, size_t ws_size,
                              hipStream_t stream) {
    const int*   obs = (const int*)d_in[0];
    const float* A   = (const float*)d_in[1];
    const float* B   = (const float*)d_in[2];
    const float* pi  = (const float*)d_in[3];
    float* out = (float*)d_out;
    unsigned* flag = (unsigned*)d_ws;

    // d_ws is poisoned before every launch; zstart word must start defined.
    (void)hipMemsetAsync(d_ws, 0, 4 * sizeof(unsigned), stream);

    hmm_fwd<<<dim3(NCBLK), dim3(CTHR), 0, stream>>>(obs, A, B, pi, out, flag);
    hmm_tail<<<dim3(FBLK), dim3(NTHR), 0, stream>>>(out, flag);
}